// Round 2
// 727.132 us; speedup vs baseline: 1.0786x; 1.0786x over previous
//
#include <hip/hip_runtime.h>
#include <math.h>
#include <stdint.h>

#define TOKENS 16384
#define HIDDEN 7168
#define NE     256
#define NGROUP 8
#define GSIZE  32
#define TOPKG  4
#define TOPK   8

#define KSPLIT 4
#define TM     64                         // tokens per block
#define BK     32
#define KC_TOTAL (HIDDEN / BK)            // 224
#define KC_SLICE (KC_TOTAL / KSPLIT)      // 56

// ws: [0, WPLANES_BYTES) fp16 W planes (frag order); then fp32 partials [KSPLIT][16384][256]
#define WPLANES_BYTES ((size_t)KC_TOTAL * 32 * 1024)   // 7,340,032

typedef _Float16 half8 __attribute__((ext_vector_type(8)));
typedef float    floatx4 __attribute__((ext_vector_type(4)));
typedef unsigned int u32;
#define GAS __attribute__((address_space(1)))
#define LAS __attribute__((address_space(3)))

// ---------------------------------------------------------------------------
// Split W fp32 -> (wh, wl*2048) fp16 planes, frag-ordered per kc-block:
// half-offset = kc*16384 + plane*8192 + et*512 + (g*16 + (e&15))*8 + j
// where e = 16*et + (e&15), k = 32*kc + g*8 + j   (verified end-to-end earlier)
// ---------------------------------------------------------------------------
__global__ void prep_w(const float* __restrict__ W, _Float16* __restrict__ wp) {
    const int c = blockIdx.x * 128 + threadIdx.x;   // k-chunk of 8 (0..895)
    const int e = blockIdx.y;
    const float* src = W + (size_t)e * HIDDEN + c * 8;
    float4 v0 = *(const float4*)src;
    float4 v1 = *(const float4*)(src + 4);
    float xv[8] = {v0.x, v0.y, v0.z, v0.w, v1.x, v1.y, v1.z, v1.w};
    half8 h, l;
    #pragma unroll
    for (int j = 0; j < 8; j++) {
        _Float16 hh = (_Float16)xv[j];
        h[j] = hh;
        l[j] = (_Float16)((xv[j] - (float)hh) * 2048.0f);
    }
    const int kc = c >> 2;
    const int g  = c & 3;
    const int lane = g * 16 + (e & 15);
    const int et   = e >> 4;
    const size_t base = (size_t)kc * 16384 + (size_t)et * 512 + (size_t)lane * 8;
    *(half8*)(wp + base)        = h;
    *(half8*)(wp + base + 8192) = l;
}

// ---------------------------------------------------------------------------
// GEMM: block = 64 tokens x 256 experts x K/4. 256 threads = 4 waves.
// KSPLIT=4 so each XCD (b&3 fixed within an XCD's stripe) streams a 1.84 MB
// wp quarter -> fully L2-resident (4 MiB/XCD).
// B double-buffered in LDS (72 KB total, 2 blocks/CU). Per iter: raw
// s_barrier + counted s_waitcnt vmcnt(8) so the 8 global_load_lds for iter
// i+1 stay in flight across the barrier (issued one full iteration ahead).
// vmcnt accounting (steady state): entry outstanding = {B(i):8, A(i):2};
// after issuing B(i+1): 18; compiler's implicit wait for A(i) regs at the
// A-stage retires B(i)+A(i) (older) -> 8; explicit vmcnt(8) is then exact.
// ---------------------------------------------------------------------------
__global__ __launch_bounds__(256, 2)
void gemm_kernel(const float* __restrict__ X, const _Float16* __restrict__ wp,
                 float* __restrict__ partial) {
    // A planes [0,4096) halves; B dbuf [4096, 36864) halves (2 x 16384)
    __shared__ __align__(16) _Float16 smem[36864];   // 72 KB

    const int tid  = threadIdx.x;
    const int b    = blockIdx.x;
    const int tb   = b >> 2;
    const int ks   = b & 3;
    const int t0   = tb * TM;

    const int w    = tid >> 6;       // wave 0..3 -> expert quarter
    const int lane = tid & 63;

    // A staging map: thread -> token at = tid>>2 (coalesced 128B row chunks), k-granule ac
    const int at = tid >> 2;
    const int ac = tid & 3;
    const int awoff = (at >> 4) * 512 + (ac * 16 + (at & 15)) * 8;  // frag-order chunk
    const float* Xrow = X + (size_t)(t0 + at) * HIDDEN + ks * (HIDDEN / KSPLIT) + ac * 8;

    const char* wbase = (const char*)wp + (size_t)ks * KC_SLICE * 32768;

    floatx4 acc0[4][4], acc1[4][4];
    #pragma unroll
    for (int i = 0; i < 4; i++)
        #pragma unroll
        for (int j = 0; j < 4; j++) {
            acc0[i][j] = (floatx4){0.f, 0.f, 0.f, 0.f};
            acc1[i][j] = (floatx4){0.f, 0.f, 0.f, 0.f};
        }

    // ---- prologue: issue B(0) into buf0 FIRST (so it is older than A loads),
    // then A regs for iter 0 ----
    {
        const char* wsrc = wbase;
        char* bdst = (char*)(smem + 4096);
        #pragma unroll
        for (int q = 0; q < 8; q++) {
            const int o = (tid + 256 * q) * 16;
            __builtin_amdgcn_global_load_lds((GAS const u32*)(wsrc + o),
                                             (LAS u32*)(bdst + o), 16, 0, 0);
        }
    }
    float4 v0 = *(const float4*)Xrow;
    float4 v1 = *(const float4*)(Xrow + 4);

    for (int i = 0; i < KC_SLICE; i++) {
        const int cur = i & 1;

        // barrier #1: all waves finished compute(i-1): frag reads of buf[cur^1]
        // and A-lds retired -> safe to overwrite both.
        asm volatile("s_barrier" ::: "memory");

        // ---- issue B(i+1) into the other buffer (stays in flight across barrier) ----
        if (i + 1 < KC_SLICE) {
            const char* wsrc = wbase + (size_t)(i + 1) * 32768;
            char* bdst = (char*)(smem + 4096 + (cur ^ 1) * 16384);
            #pragma unroll
            for (int q = 0; q < 8; q++) {
                const int o = (tid + 256 * q) * 16;
                __builtin_amdgcn_global_load_lds((GAS const u32*)(wsrc + o),
                                                 (LAS u32*)(bdst + o), 16, 0, 0);
            }
        }

        // ---- stage A(i): split prefetched regs into 2 fp16 planes, frag-order ----
        {
            float xv[8] = {v0.x, v0.y, v0.z, v0.w, v1.x, v1.y, v1.z, v1.w};
            half8 ahh, ahl;
            #pragma unroll
            for (int j = 0; j < 8; j++) {
                _Float16 hh = (_Float16)xv[j];
                ahh[j] = hh;
                ahl[j] = (_Float16)((xv[j] - (float)hh) * 2048.0f);
            }
            *(half8*)(smem + awoff)        = ahh;
            *(half8*)(smem + 2048 + awoff) = ahl;
        }

        // ---- drain: B(i) complete (8 newest = B(i+1) may remain), A writes done ----
        if (i + 1 < KC_SLICE) {
            asm volatile("s_waitcnt vmcnt(8) lgkmcnt(0)" ::: "memory");
            __builtin_amdgcn_sched_barrier(0);   // rule #18: pin ops below the wait
            // prefetch next iter's A into regs (in flight across barrier, hidden under MFMAs)
            const float* xp = Xrow + (size_t)(i + 1) * BK;
            v0 = *(const float4*)xp;
            v1 = *(const float4*)(xp + 4);
        } else {
            asm volatile("s_waitcnt vmcnt(0) lgkmcnt(0)" ::: "memory");
            __builtin_amdgcn_sched_barrier(0);
        }

        // barrier #2: every wave has drained its own staging -> buf[cur] + A valid
        asm volatile("s_barrier" ::: "memory");

        // ---- fragments + 48 MFMA (dependent acc1 pairs separated by et sweep) ----
        const _Float16* Bb = smem + 4096 + cur * 16384 + w * 2048;   // expert quarter, plane0
        half8 bh[4], bl[4];
        #pragma unroll
        for (int et = 0; et < 4; et++) {
            bh[et] = *(const half8*)(Bb + et * 512 + lane * 8);
            bl[et] = *(const half8*)(Bb + 8192 + et * 512 + lane * 8);
        }
        #pragma unroll
        for (int mt = 0; mt < 4; mt++) {
            half8 ah = *(const half8*)(smem + mt * 512 + lane * 8);
            half8 al = *(const half8*)(smem + 2048 + mt * 512 + lane * 8);
            #pragma unroll
            for (int et = 0; et < 4; et++)
                acc0[mt][et] = __builtin_amdgcn_mfma_f32_16x16x32_f16(ah, bh[et], acc0[mt][et], 0, 0, 0);
            #pragma unroll
            for (int et = 0; et < 4; et++)
                acc1[mt][et] = __builtin_amdgcn_mfma_f32_16x16x32_f16(ah, bl[et], acc1[mt][et], 0, 0, 0);
            #pragma unroll
            for (int et = 0; et < 4; et++)
                acc1[mt][et] = __builtin_amdgcn_mfma_f32_16x16x32_f16(al, bh[et], acc1[mt][et], 0, 0, 0);
        }
    }

    // ---- epilogue: combine planes, write fp32 partials [ks][t][e] ----
    float* P = partial + (size_t)ks * TOKENS * NE;
    const float inv = 1.0f / 2048.0f;
    #pragma unroll
    for (int mt = 0; mt < 4; mt++)
        #pragma unroll
        for (int et = 0; et < 4; et++) {
            floatx4 r = acc0[mt][et] + acc1[mt][et] * inv;
            const int col = w * 64 + 16 * et + (lane & 15);
            const int row = t0 + 16 * mt + (lane >> 4) * 4;
            #pragma unroll
            for (int rr = 0; rr < 4; rr++)
                P[(size_t)(row + rr) * NE + col] = r[rr];
        }
}

// ---------------------------------------------------------------------------
// Selection: one wave per token (4 tokens / 256-thread block). Lane l owns
// experts 4l..4l+3; everything in registers with STATIC indexing (no scratch),
// group-top2 / group-rank / 8 argmax rounds via __shfl_xor butterflies.
// Tie-breaking: strict '>' with lowest-index-wins, matching jax top_k and
// the previously verified serial implementation exactly.
// ---------------------------------------------------------------------------
__global__ __launch_bounds__(256)
void select_kernel(const float* __restrict__ partial, const float* __restrict__ bias,
                   float* __restrict__ out) {
    const int lane = threadIdx.x & 63;
    const int t    = blockIdx.x * 4 + (threadIdx.x >> 6);
    const int e0   = lane * 4;

    float lg[4] = {0.f, 0.f, 0.f, 0.f};
    #pragma unroll
    for (int s = 0; s < KSPLIT; s++) {
        float4 p = *(const float4*)(partial + ((size_t)s * TOKENS + t) * NE + e0);
        lg[0] += p.x; lg[1] += p.y; lg[2] += p.z; lg[3] += p.w;
    }
    float4 b4 = *(const float4*)(bias + e0);
    const float bb[4] = {b4.x, b4.y, b4.z, b4.w};

    float sig[4], sfc[4];
    #pragma unroll
    for (int j = 0; j < 4; j++) {
        sig[j] = 1.0f / (1.0f + expf(-lg[j]));
        sfc[j] = sig[j] + bb[j];
    }

    // ---- group top-2 (group g = experts 32g..32g+31 = lanes 8g..8g+7) ----
    float m1 = sfc[0], m2 = -INFINITY;
    #pragma unroll
    for (int j = 1; j < 4; j++) {
        if (sfc[j] > m1)      { m2 = m1; m1 = sfc[j]; }
        else if (sfc[j] > m2) { m2 = sfc[j]; }
    }
    #pragma unroll
    for (int d = 1; d < 8; d <<= 1) {
        float o1 = __shfl_xor(m1, d);
        float o2 = __shfl_xor(m2, d);
        float hi = fmaxf(m1, o1);
        float lo = fmaxf(fminf(m1, o1), fmaxf(m2, o2));
        m1 = hi; m2 = lo;
    }
    const float gscore = m1 + m2;          // uniform within 8-lane group
    const int mygroup = lane >> 3;

    // ---- rank of my group among 8 (ties -> lower index first) ----
    int rank = 0;
    #pragma unroll
    for (int g = 0; g < 8; g++) {
        float gs = __shfl(gscore, g * 8);
        rank += (gs > gscore) || (gs == gscore && g < mygroup);
    }
    const bool keep = (rank < TOPKG);

    // masked_scores = scores_for_choice * mask (dropped -> exactly 0, selectable)
    float cand[4];
    #pragma unroll
    for (int j = 0; j < 4; j++) cand[j] = keep ? sfc[j] : 0.0f;

    float wr[TOPK]; int er[TOPK]; float wsum = 0.f;
    #pragma unroll
    for (int r = 0; r < TOPK; r++) {
        // local argmax (lowest j wins ties)
        float bv = cand[0]; int bj = 0;
        #pragma unroll
        for (int j = 1; j < 4; j++) if (cand[j] > bv) { bv = cand[j]; bj = j; }
        int be = e0 + bj;
        // wave argmax butterfly (lower expert index wins ties)
        #pragma unroll
        for (int d = 1; d < 64; d <<= 1) {
            float ov = __shfl_xor(bv, d);
            int   oe = __shfl_xor(be, d);
            if (ov > bv || (ov == bv && oe < be)) { bv = ov; be = oe; }
        }
        const int ol = be >> 2, oj = be & 3;     // uniform
        float osig = (oj == 0) ? sig[0] : (oj == 1) ? sig[1] : (oj == 2) ? sig[2] : sig[3];
        float wv = __shfl(osig, ol);             // unmasked sigmoid score of winner
        wr[r] = wv; er[r] = be; wsum += wv;
        // remove winner (static indices only)
        const bool own = (ol == lane);
        cand[0] = (own && oj == 0) ? -INFINITY : cand[0];
        cand[1] = (own && oj == 1) ? -INFINITY : cand[1];
        cand[2] = (own && oj == 2) ? -INFINITY : cand[2];
        cand[3] = (own && oj == 3) ? -INFINITY : cand[3];
    }

    const float scale = 2.5f / (wsum + 1e-20f);
    if (lane == 0) {
        #pragma unroll
        for (int r = 0; r < TOPK; r++) {
            out[(size_t)t * TOPK + r] = wr[r] * scale;
            out[(size_t)TOKENS * TOPK + (size_t)t * TOPK + r] = (float)er[r];
        }
    }
}

extern "C" void kernel_launch(void* const* d_in, const int* in_sizes, int n_in,
                              void* d_out, int out_size, void* d_ws, size_t ws_size,
                              hipStream_t stream) {
    const float* X  = (const float*)d_in[0];
    const float* W  = (const float*)d_in[1];
    const float* eb = (const float*)d_in[2];
    float* out = (float*)d_out;

    _Float16* wp   = (_Float16*)d_ws;
    float* partial = (float*)((char*)d_ws + WPLANES_BYTES);

    hipLaunchKernelGGL(prep_w, dim3(7, 256), dim3(128), 0, stream, W, wp);
    hipLaunchKernelGGL(gemm_kernel, dim3(TOKENS / TM * KSPLIT), dim3(256), 0, stream, X, wp, partial);
    hipLaunchKernelGGL(select_kernel, dim3(TOKENS / 4), dim3(256), 0, stream, partial, eb, out);
}

// Round 4
// 701.954 us; speedup vs baseline: 1.1173x; 1.0359x over previous
//
#include <hip/hip_runtime.h>
#include <math.h>
#include <stdint.h>

#define TOKENS 16384
#define HIDDEN 7168
#define NE     256
#define NGROUP 8
#define GSIZE  32
#define TOPKG  4
#define TOPK   8

#define KSPLIT 4
#define TM     64                         // tokens per block
#define BK     32
#define KC_TOTAL (HIDDEN / BK)            // 224
#define KC_SLICE (KC_TOTAL / KSPLIT)      // 56

// ws: [0, WPLANES_BYTES) fp16 W planes (frag order); then fp32 partials [KSPLIT][16384][256]
#define WPLANES_BYTES ((size_t)KC_TOTAL * 32 * 1024)   // 7,340,032

typedef _Float16 half8 __attribute__((ext_vector_type(8)));
typedef float    floatx4 __attribute__((ext_vector_type(4)));
typedef unsigned int u32;
#define GAS __attribute__((address_space(1)))
#define LAS __attribute__((address_space(3)))

// ---------------------------------------------------------------------------
// Split W fp32 -> (wh, wl*2048) fp16 planes, frag-ordered per kc-block:
// half-offset = kc*16384 + plane*8192 + et*512 + (g*16 + (e&15))*8 + j
// where e = 16*et + (e&15), k = 32*kc + g*8 + j   (verified end-to-end earlier)
// ---------------------------------------------------------------------------
__global__ void prep_w(const float* __restrict__ W, _Float16* __restrict__ wp) {
    const int c = blockIdx.x * 128 + threadIdx.x;   // k-chunk of 8 (0..895)
    const int e = blockIdx.y;
    const float* src = W + (size_t)e * HIDDEN + c * 8;
    float4 v0 = *(const float4*)src;
    float4 v1 = *(const float4*)(src + 4);
    float xv[8] = {v0.x, v0.y, v0.z, v0.w, v1.x, v1.y, v1.z, v1.w};
    half8 h, l;
    #pragma unroll
    for (int j = 0; j < 8; j++) {
        _Float16 hh = (_Float16)xv[j];
        h[j] = hh;
        l[j] = (_Float16)((xv[j] - (float)hh) * 2048.0f);
    }
    const int kc = c >> 2;
    const int g  = c & 3;
    const int lane = g * 16 + (e & 15);
    const int et   = e >> 4;
    const size_t base = (size_t)kc * 16384 + (size_t)et * 512 + (size_t)lane * 8;
    *(half8*)(wp + base)        = h;
    *(half8*)(wp + base + 8192) = l;
}

// ---------------------------------------------------------------------------
// GEMM: block = 64 tokens x 256 experts x K/4. 256 threads = 4 waves.
// KSPLIT=4: each XCD streams a 1.84 MB wp quarter -> L2-resident.
// B double-buffered in LDS; X register-prefetch is 2 ITERATIONS deep
// (unroll-by-2, two named float4 pairs -> static regs, no scratch).
// vmcnt accounting, steady state at the counted wait:
//   queue (old->new): X(i):2, B(i):8, X(i+1):2, B(i+1):8  (20 total)
//   implicit wait for X(i) at A-stage -> <=18; explicit vmcnt(10) retires
//   B(i), leaves {X(i+1):2, B(i+1):8}; then issue X(i+2) -> 12 = next entry.
// Tail (i+1==KC_SLICE): queue = B(i):8 only -> vmcnt(0).
// Worst-case compiler reordering (X(i+2) hoisted above the wait) only
// over-drains (correct, less overlap) — counted waits cannot hang.
// ---------------------------------------------------------------------------
__global__ __launch_bounds__(256, 2)
void gemm_kernel(const float* __restrict__ X, const _Float16* __restrict__ wp,
                 float* __restrict__ partial) {
    // A planes [0,4096) halves; B dbuf [4096, 36864) halves (2 x 16384)
    __shared__ __align__(16) _Float16 smem[36864];   // 72 KB

    const int tid  = threadIdx.x;
    const int b    = blockIdx.x;
    const int tb   = b >> 2;
    const int ks   = b & 3;
    const int t0   = tb * TM;

    const int w    = tid >> 6;       // wave 0..3 -> expert quarter
    const int lane = tid & 63;

    // A staging map: thread -> token at = tid>>2 (coalesced 128B row chunks), k-granule ac
    const int at = tid >> 2;
    const int ac = tid & 3;
    const int awoff = (at >> 4) * 512 + (ac * 16 + (at & 15)) * 8;  // frag-order chunk
    const float* Xrow = X + (size_t)(t0 + at) * HIDDEN + ks * (HIDDEN / KSPLIT) + ac * 8;

    const char* wbase = (const char*)wp + (size_t)ks * KC_SLICE * 32768;

    floatx4 acc0[4][4], acc1[4][4];
    #pragma unroll
    for (int i = 0; i < 4; i++)
        #pragma unroll
        for (int j = 0; j < 4; j++) {
            acc0[i][j] = (floatx4){0.f, 0.f, 0.f, 0.f};
            acc1[i][j] = (floatx4){0.f, 0.f, 0.f, 0.f};
        }

    // ---- prologue: B(0) first (oldest in queue), then X(0) and X(1) regs ----
    {
        const char* wsrc = wbase;
        char* bdst = (char*)(smem + 4096);
        #pragma unroll
        for (int q = 0; q < 8; q++) {
            const int o = (tid + 256 * q) * 16;
            __builtin_amdgcn_global_load_lds((GAS const u32*)(wsrc + o),
                                             (LAS u32*)(bdst + o), 16, 0, 0);
        }
    }
    float4 xa0 = *(const float4*)Xrow;            // X(0)
    float4 xa1 = *(const float4*)(Xrow + 4);
    float4 xb0 = *(const float4*)(Xrow + BK);     // X(1)
    float4 xb1 = *(const float4*)(Xrow + BK + 4);

#define GEMM_BODY(I, X0, X1)                                                      \
    {                                                                             \
        const int i   = (I);                                                      \
        const int cur = i & 1;                                                    \
        /* barrier #1: compute(i-1) frag reads retired -> safe to overwrite */    \
        asm volatile("s_barrier" ::: "memory");                                   \
        /* issue B(i+1) into the other buffer (in flight across barriers) */      \
        if (i + 1 < KC_SLICE) {                                                   \
            const char* wsrc = wbase + (size_t)(i + 1) * 32768;                   \
            char* bdst = (char*)(smem + 4096 + (cur ^ 1) * 16384);                \
            _Pragma("unroll")                                                     \
            for (int q = 0; q < 8; q++) {                                         \
                const int o = (tid + 256 * q) * 16;                               \
                __builtin_amdgcn_global_load_lds((GAS const u32*)(wsrc + o),      \
                                                 (LAS u32*)(bdst + o), 16, 0, 0); \
            }                                                                     \
        }                                                                         \
        /* stage A(i): split prefetched regs into 2 fp16 planes, frag-order */    \
        {                                                                         \
            float xv[8] = {X0.x, X0.y, X0.z, X0.w, X1.x, X1.y, X1.z, X1.w};       \
            half8 ahh, ahl;                                                       \
            _Pragma("unroll")                                                     \
            for (int j = 0; j < 8; j++) {                                         \
                _Float16 hh = (_Float16)xv[j];                                    \
                ahh[j] = hh;                                                      \
                ahl[j] = (_Float16)((xv[j] - (float)hh) * 2048.0f);               \
            }                                                                     \
            *(half8*)(smem + awoff)        = ahh;                                 \
            *(half8*)(smem + 2048 + awoff) = ahl;                                 \
        }                                                                         \
        /* drain: B(i) complete; X(i+1)+B(i+1) stay in flight */                  \
        if (i + 1 < KC_SLICE) {                                                   \
            asm volatile("s_waitcnt vmcnt(10) lgkmcnt(0)" ::: "memory");          \
        } else {                                                                  \
            asm volatile("s_waitcnt vmcnt(0) lgkmcnt(0)" ::: "memory");           \
        }                                                                         \
        __builtin_amdgcn_sched_barrier(0);                                        \
        /* issue X(i+2) into the just-freed named pair (2-deep pipeline) */       \
        if (i + 2 < KC_SLICE) {                                                   \
            const float* xp = Xrow + (size_t)(i + 2) * BK;                        \
            X0 = *(const float4*)xp;                                              \
            X1 = *(const float4*)(xp + 4);                                        \
        }                                                                         \
        /* barrier #2: all waves staged -> buf[cur] + A valid */                  \
        asm volatile("s_barrier" ::: "memory");                                   \
        /* fragments + 48 MFMA */                                                 \
        const _Float16* Bb = smem + 4096 + cur * 16384 + w * 2048;                \
        half8 bh[4], bl[4];                                                       \
        _Pragma("unroll")                                                         \
        for (int et = 0; et < 4; et++) {                                          \
            bh[et] = *(const half8*)(Bb + et * 512 + lane * 8);                   \
            bl[et] = *(const half8*)(Bb + 8192 + et * 512 + lane * 8);            \
        }                                                                         \
        _Pragma("unroll")                                                         \
        for (int mt = 0; mt < 4; mt++) {                                          \
            half8 ah = *(const half8*)(smem + mt * 512 + lane * 8);               \
            half8 al = *(const half8*)(smem + 2048 + mt * 512 + lane * 8);        \
            _Pragma("unroll")                                                     \
            for (int et = 0; et < 4; et++)                                        \
                acc0[mt][et] = __builtin_amdgcn_mfma_f32_16x16x32_f16(            \
                    ah, bh[et], acc0[mt][et], 0, 0, 0);                           \
            _Pragma("unroll")                                                     \
            for (int et = 0; et < 4; et++)                                        \
                acc1[mt][et] = __builtin_amdgcn_mfma_f32_16x16x32_f16(            \
                    ah, bl[et], acc1[mt][et], 0, 0, 0);                           \
            _Pragma("unroll")                                                     \
            for (int et = 0; et < 4; et++)                                        \
                acc1[mt][et] = __builtin_amdgcn_mfma_f32_16x16x32_f16(            \
                    al, bh[et], acc1[mt][et], 0, 0, 0);                           \
        }                                                                         \
    }

    for (int ii = 0; ii < KC_SLICE; ii += 2) {
        GEMM_BODY(ii,     xa0, xa1);
        GEMM_BODY(ii + 1, xb0, xb1);
    }
#undef GEMM_BODY

    // ---- epilogue: combine planes, write fp32 partials [ks][t][e] ----
    float* P = partial + (size_t)ks * TOKENS * NE;
    const float inv = 1.0f / 2048.0f;
    #pragma unroll
    for (int mt = 0; mt < 4; mt++)
        #pragma unroll
        for (int et = 0; et < 4; et++) {
            floatx4 r = acc0[mt][et] + acc1[mt][et] * inv;
            const int col = w * 64 + 16 * et + (lane & 15);
            const int row = t0 + 16 * mt + (lane >> 4) * 4;
            #pragma unroll
            for (int rr = 0; rr < 4; rr++)
                P[(size_t)(row + rr) * NE + col] = r[rr];
        }
}

// ---------------------------------------------------------------------------
// Selection: one wave per token (4 tokens / 256-thread block). Lane l owns
// experts 4l..4l+3; everything in registers with STATIC indexing (no scratch),
// group-top2 / group-rank / 8 argmax rounds via __shfl_xor butterflies.
// Tie-breaking: strict '>' with lowest-index-wins, matching jax top_k and
// the previously verified serial implementation exactly.
// ---------------------------------------------------------------------------
__global__ __launch_bounds__(256)
void select_kernel(const float* __restrict__ partial, const float* __restrict__ bias,
                   float* __restrict__ out) {
    const int lane = threadIdx.x & 63;
    const int t    = blockIdx.x * 4 + (threadIdx.x >> 6);
    const int e0   = lane * 4;

    float lg[4] = {0.f, 0.f, 0.f, 0.f};
    #pragma unroll
    for (int s = 0; s < KSPLIT; s++) {
        float4 p = *(const float4*)(partial + ((size_t)s * TOKENS + t) * NE + e0);
        lg[0] += p.x; lg[1] += p.y; lg[2] += p.z; lg[3] += p.w;
    }
    float4 b4 = *(const float4*)(bias + e0);
    const float bb[4] = {b4.x, b4.y, b4.z, b4.w};

    float sig[4], sfc[4];
    #pragma unroll
    for (int j = 0; j < 4; j++) {
        sig[j] = 1.0f / (1.0f + expf(-lg[j]));
        sfc[j] = sig[j] + bb[j];
    }

    // ---- group top-2 (group g = experts 32g..32g+31 = lanes 8g..8g+7) ----
    float m1 = sfc[0], m2 = -INFINITY;
    #pragma unroll
    for (int j = 1; j < 4; j++) {
        if (sfc[j] > m1)      { m2 = m1; m1 = sfc[j]; }
        else if (sfc[j] > m2) { m2 = sfc[j]; }
    }
    #pragma unroll
    for (int d = 1; d < 8; d <<= 1) {
        float o1 = __shfl_xor(m1, d);
        float o2 = __shfl_xor(m2, d);
        float hi = fmaxf(m1, o1);
        float lo = fmaxf(fminf(m1, o1), fmaxf(m2, o2));
        m1 = hi; m2 = lo;
    }
    const float gscore = m1 + m2;          // uniform within 8-lane group
    const int mygroup = lane >> 3;

    // ---- rank of my group among 8 (ties -> lower index first) ----
    int rank = 0;
    #pragma unroll
    for (int g = 0; g < 8; g++) {
        float gs = __shfl(gscore, g * 8);
        rank += (gs > gscore) || (gs == gscore && g < mygroup);
    }
    const bool keep = (rank < TOPKG);

    // masked_scores = scores_for_choice * mask (dropped -> exactly 0, selectable)
    float cand[4];
    #pragma unroll
    for (int j = 0; j < 4; j++) cand[j] = keep ? sfc[j] : 0.0f;

    float wr[TOPK]; int er[TOPK]; float wsum = 0.f;
    #pragma unroll
    for (int r = 0; r < TOPK; r++) {
        // local argmax (lowest j wins ties)
        float bv = cand[0]; int bj = 0;
        #pragma unroll
        for (int j = 1; j < 4; j++) if (cand[j] > bv) { bv = cand[j]; bj = j; }
        int be = e0 + bj;
        // wave argmax butterfly (lower expert index wins ties)
        #pragma unroll
        for (int d = 1; d < 64; d <<= 1) {
            float ov = __shfl_xor(bv, d);
            int   oe = __shfl_xor(be, d);
            if (ov > bv || (ov == bv && oe < be)) { bv = ov; be = oe; }
        }
        const int ol = be >> 2, oj = be & 3;     // uniform
        float osig = (oj == 0) ? sig[0] : (oj == 1) ? sig[1] : (oj == 2) ? sig[2] : sig[3];
        float wv = __shfl(osig, ol);             // unmasked sigmoid score of winner
        wr[r] = wv; er[r] = be; wsum += wv;
        // remove winner (static indices only)
        const bool own = (ol == lane);
        cand[0] = (own && oj == 0) ? -INFINITY : cand[0];
        cand[1] = (own && oj == 1) ? -INFINITY : cand[1];
        cand[2] = (own && oj == 2) ? -INFINITY : cand[2];
        cand[3] = (own && oj == 3) ? -INFINITY : cand[3];
    }

    const float scale = 2.5f / (wsum + 1e-20f);
    if (lane == 0) {
        #pragma unroll
        for (int r = 0; r < TOPK; r++) {
            out[(size_t)t * TOPK + r] = wr[r] * scale;
            out[(size_t)TOKENS * TOPK + (size_t)t * TOPK + r] = (float)er[r];
        }
    }
}

extern "C" void kernel_launch(void* const* d_in, const int* in_sizes, int n_in,
                              void* d_out, int out_size, void* d_ws, size_t ws_size,
                              hipStream_t stream) {
    const float* X  = (const float*)d_in[0];
    const float* W  = (const float*)d_in[1];
    const float* eb = (const float*)d_in[2];
    float* out = (float*)d_out;

    _Float16* wp   = (_Float16*)d_ws;
    float* partial = (float*)((char*)d_ws + WPLANES_BYTES);

    hipLaunchKernelGGL(prep_w, dim3(7, 256), dim3(128), 0, stream, W, wp);
    hipLaunchKernelGGL(gemm_kernel, dim3(TOKENS / TM * KSPLIT), dim3(256), 0, stream, X, wp, partial);
    hipLaunchKernelGGL(select_kernel, dim3(TOKENS / 4), dim3(256), 0, stream, partial, eb, out);
}